// Round 8
// baseline (138.049 us; speedup 1.0000x reference)
//
#include <hip/hip_runtime.h>

// Problem constants
#define B_SIZE 16384
#define D_DIM  1024
#define T_DIM  128
#define VLn    12
#define BM     32             // rows per block
#define NCHUNK 16             // K chunks of 64
#define GRID   (B_SIZE / BM)  // 512
#define SL_STRIDE 132

typedef _Float16 half8  __attribute__((ext_vector_type(8)));
typedef __fp16   fp16x2 __attribute__((ext_vector_type(2)));
typedef float    f32x4  __attribute__((ext_vector_type(4)));

union Pack16 { fp16x2 h[4]; uint4 u; half8 v; };
union BReg   { uint4 u; half8 h; };

__device__ __forceinline__ half8 pack8h(float4 v0, float4 v1) {
    Pack16 un;
    un.h[0] = __builtin_amdgcn_cvt_pkrtz(v0.x, v0.y);
    un.h[1] = __builtin_amdgcn_cvt_pkrtz(v0.z, v0.w);
    un.h[2] = __builtin_amdgcn_cvt_pkrtz(v1.x, v1.y);
    un.h[3] = __builtin_amdgcn_cvt_pkrtz(v1.z, v1.w);
    return un.v;
}
__device__ __forceinline__ uint4 pack8u(float4 v0, float4 v1) {
    Pack16 un;
    un.h[0] = __builtin_amdgcn_cvt_pkrtz(v0.x, v0.y);
    un.h[1] = __builtin_amdgcn_cvt_pkrtz(v0.z, v0.w);
    un.h[2] = __builtin_amdgcn_cvt_pkrtz(v1.x, v1.y);
    un.h[3] = __builtin_amdgcn_cvt_pkrtz(v1.z, v1.w);
    return un.u;
}

// W fp32 [128][1024] -> f16, swizzled into MFMA B-fragment order:
// unit j (16 B = 8 f16): kc=j>>10, g=(j&1023)>>6 (g = ks*8+CT), lane=j&63;
// holds W[n = CT*16 + (lane&15)][k = kc*64 + ks*32 + (lane>>4)*8 .. +8].
__global__ __launch_bounds__(256)
void conv_w(const float* __restrict__ W, uint4* __restrict__ Wf) {
    const int j    = blockIdx.x * 256 + threadIdx.x;   // 0..16383
    const int kc   = j >> 10;
    const int r    = j & 1023;
    const int g    = r >> 6;
    const int lane = r & 63;
    const int ks = g >> 3, CT = g & 7;
    const int n = CT * 16 + (lane & 15);
    const int k = kc * 64 + ks * 32 + ((lane >> 4) << 3);
    const float* src = W + (size_t)n * D_DIM + k;
    const float4 v0 = *(const float4*)src;
    const float4 v1 = *(const float4*)(src + 4);
    Wf[j] = pack8u(v0, v1);
}

// 512 blocks x 256 threads (4 waves) = 2 blocks/CU.
// Block = 32 rows x 128 cols x full K. Wave w owns cols [w*32, w*32+32).
// K-loop: ZERO LDS, ZERO barriers. A fragments loaded per-lane from emb
// (4-way wave redundancy absorbed by L1); B fragments direct from swizzled
// Wf (L2-resident). 1-chunk register pipeline; waves slip freely.
__global__ __launch_bounds__(256, 2)
void qloss_kernel(const float* __restrict__ emb,
                  const uint4* __restrict__ Wf,
                  const float* __restrict__ bias,
                  const int*   __restrict__ didx,
                  const int*   __restrict__ dmsk,
                  float*       __restrict__ out)
{
    __shared__ __align__(16) unsigned char smem[16912];
    float* sL   = (float*)smem;                  // [32][132] f32 epilogue
    float* sRed = (float*)(smem + 16896);

    const int t    = threadIdx.x;
    const int w    = t >> 6;
    const int lane = t & 63;
    const int m15  = lane & 15;
    const int quad = lane >> 4;
    const int r0   = blockIdx.x * BM;

    // A-frag (mt, ks): emb[(r0 + mt*16 + m15)*1024 + kc*64 + ks*32 + quad*8 .. +8]
    const float* aR0 = emb + (size_t)(r0 + m15) * D_DIM + quad * 8;
    const float* aR1 = aR0 + 16 * D_DIM;
    // B-frag (ks, j): Wf[kc*1024 + (ks*8 + 2w+j)*64 + lane]
    const uint4* bP  = Wf + (size_t)(2 * w) * 64 + lane;

    f32x4 acc[2][2];
#pragma unroll
    for (int mt = 0; mt < 2; ++mt)
#pragma unroll
        for (int ct = 0; ct < 2; ++ct) acc[mt][ct] = (f32x4){0.f, 0.f, 0.f, 0.f};

    // pipeline registers: chunk-current raw A (8 x float4) + B (4 frags)
    float4 ac[8], an[8];
    BReg   bc[4], bn[4];

    // prologue: issue chunk 0 loads
#pragma unroll
    for (int mt = 0; mt < 2; ++mt)
#pragma unroll
        for (int ks = 0; ks < 2; ++ks) {
            const float* p = (mt ? aR1 : aR0) + ks * 32;
            ac[mt * 4 + ks * 2 + 0] = *(const float4*)(p);
            ac[mt * 4 + ks * 2 + 1] = *(const float4*)(p + 4);
        }
#pragma unroll
    for (int ks = 0; ks < 2; ++ks)
#pragma unroll
        for (int j = 0; j < 2; ++j)
            bc[ks * 2 + j].u = bP[(size_t)(ks * 8 + j) * 64];

#pragma unroll
    for (int kc = 0; kc < NCHUNK; ++kc) {
        // issue chunk kc+1 loads (in flight across this chunk's pack+MFMA)
        if (kc + 1 < NCHUNK) {
            const int ko = (kc + 1) * 64;
#pragma unroll
            for (int mt = 0; mt < 2; ++mt)
#pragma unroll
                for (int ks = 0; ks < 2; ++ks) {
                    const float* p = (mt ? aR1 : aR0) + ko + ks * 32;
                    an[mt * 4 + ks * 2 + 0] = *(const float4*)(p);
                    an[mt * 4 + ks * 2 + 1] = *(const float4*)(p + 4);
                }
#pragma unroll
            for (int ks = 0; ks < 2; ++ks)
#pragma unroll
                for (int j = 0; j < 2; ++j)
                    bn[ks * 2 + j].u = bP[(size_t)(kc + 1) * 1024 + (ks * 8 + j) * 64];
        }

        // compute chunk kc
#pragma unroll
        for (int ks = 0; ks < 2; ++ks) {
            const half8 a0 = pack8h(ac[0 + ks * 2], ac[1 + ks * 2]);
            const half8 a1 = pack8h(ac[4 + ks * 2], ac[5 + ks * 2]);
            acc[0][0] = __builtin_amdgcn_mfma_f32_16x16x32_f16(a0, bc[ks * 2 + 0].h, acc[0][0], 0, 0, 0);
            acc[0][1] = __builtin_amdgcn_mfma_f32_16x16x32_f16(a0, bc[ks * 2 + 1].h, acc[0][1], 0, 0, 0);
            acc[1][0] = __builtin_amdgcn_mfma_f32_16x16x32_f16(a1, bc[ks * 2 + 0].h, acc[1][0], 0, 0, 0);
            acc[1][1] = __builtin_amdgcn_mfma_f32_16x16x32_f16(a1, bc[ks * 2 + 1].h, acc[1][1], 0, 0, 0);
        }

        // rotate pipeline (register renaming under full unroll)
#pragma unroll
        for (int q = 0; q < 8; ++q) ac[q] = an[q];
#pragma unroll
        for (int q = 0; q < 4; ++q) bc[q] = bn[q];
    }

    // ---- epilogue (first barrier of the kernel) ----
    const int CT0 = w * 2;
    const float b0v = bias[CT0 * 16 + m15];
    const float b1v = bias[(CT0 + 1) * 16 + m15];
#pragma unroll
    for (int mt = 0; mt < 2; ++mt)
#pragma unroll
        for (int i = 0; i < 4; ++i) {
            const int row = mt * 16 + quad * 4 + i;
            sL[row * SL_STRIDE + CT0 * 16 + m15]       = acc[mt][0][i] + b0v;
            sL[row * SL_STRIDE + (CT0 + 1) * 16 + m15] = acc[mt][1][i] + b1v;
        }
    __syncthreads();

    // softmax: 8 threads/row, 16 cols each
    {
        const int row = t >> 3, s = t & 7;
        float* base = &sL[row * SL_STRIDE + s * 16];
        float v[16];
#pragma unroll
        for (int j = 0; j < 4; ++j) *(float4*)&v[j * 4] = *(const float4*)(base + j * 4);
        float m = -1e30f;
#pragma unroll
        for (int j = 0; j < 16; ++j) m = fmaxf(m, v[j]);
#pragma unroll
        for (int off = 1; off < 8; off <<= 1) m = fmaxf(m, __shfl_xor(m, off));
        float ssum = 0.f;
#pragma unroll
        for (int j = 0; j < 16; ++j) { v[j] = __expf(v[j] - m); ssum += v[j]; }
#pragma unroll
        for (int off = 1; off < 8; off <<= 1) ssum += __shfl_xor(ssum, off);
        const float inv = 1.0f / ssum;
#pragma unroll
        for (int j = 0; j < 16; ++j) v[j] *= inv;
#pragma unroll
        for (int j = 0; j < 4; ++j) *(float4*)(base + j * 4) = *(const float4*)&v[j * 4];
    }
    __syncthreads();

    // gather: 384 (row, j) entries; block partial -> one atomicAdd
    float p = 0.f;
#pragma unroll
    for (int i = t; i < BM * VLn; i += 256) {
        const int gi  = r0 * VLn + i;
        const int row = i / VLn;
        const int idx = didx[gi];
        const int mk  = dmsk[gi];
        p += mk ? sL[row * SL_STRIDE + idx] : 0.f;
    }
#pragma unroll
    for (int off = 1; off < 64; off <<= 1) p += __shfl_xor(p, off);
    if (lane == 0) sRed[w] = p;
    __syncthreads();
    if (t == 0)
        atomicAdd(out, (sRed[0] + sRed[1] + sRed[2] + sRed[3]) * (1.0f / 65536.0f));
}

extern "C" void kernel_launch(void* const* d_in, const int* in_sizes, int n_in,
                              void* d_out, int out_size, void* d_ws, size_t ws_size,
                              hipStream_t stream) {
    const float* emb  = (const float*)d_in[0];
    const float* W    = (const float*)d_in[1];
    const float* bias = (const float*)d_in[2];
    const int*   didx = (const int*)d_in[3];
    const int*   dmsk = (const int*)d_in[4];
    float* out = (float*)d_out;

    uint4* Wf = (uint4*)d_ws;   // 256 KB swizzled f16 W

    hipMemsetAsync(out, 0, sizeof(float), stream);
    conv_w<<<64, 256, 0, stream>>>(W, Wf);
    qloss_kernel<<<GRID, 256, 0, stream>>>(emb, Wf, bias, didx, dmsk, out);
}

// Round 9
// 123.788 us; speedup vs baseline: 1.1152x; 1.1152x over previous
//
#include <hip/hip_runtime.h>

// Problem constants
#define B_SIZE 16384
#define D_DIM  1024
#define T_DIM  128
#define VLn    12
#define BM     32             // rows per block (2 x 16-row m-tile groups)
#define NCHUNK 16             // K chunks of 64
#define GRID   (B_SIZE / BM)  // 512
#define SL_STRIDE 132
#define A_UNITS 2097152       // 1024 mtg * 16 kc * 2 ks * 64 lanes
#define W_UNITS 16384

typedef _Float16 half8  __attribute__((ext_vector_type(8)));
typedef __fp16   fp16x2 __attribute__((ext_vector_type(2)));
typedef float    f32x4  __attribute__((ext_vector_type(4)));

union Pack16 { fp16x2 h[4]; uint4 u; half8 v; };
union Frag   { uint4 u; half8 h; };

__device__ __forceinline__ uint4 pack8u(float4 v0, float4 v1) {
    Pack16 un;
    un.h[0] = __builtin_amdgcn_cvt_pkrtz(v0.x, v0.y);
    un.h[1] = __builtin_amdgcn_cvt_pkrtz(v0.z, v0.w);
    un.h[2] = __builtin_amdgcn_cvt_pkrtz(v1.x, v1.y);
    un.h[3] = __builtin_amdgcn_cvt_pkrtz(v1.z, v1.w);
    return un.u;
}

// Pre-swizzle BOTH operands to f16 MFMA fragment order (one launch).
// Af unit u = ((mtg*16 + kc)*2 + ks)*64 + lane:
//   A[row = mtg*16 + (lane&15)][k = kc*64 + ks*32 + (lane>>4)*8 .. +8]
// Wf unit j = kc*1024 + (ks*8 + CT)*64 + lane:
//   W[n = CT*16 + (lane&15)][k = kc*64 + ks*32 + (lane>>4)*8 .. +8]
__global__ __launch_bounds__(256)
void conv_ab(const float* __restrict__ emb, const float* __restrict__ W,
             uint4* __restrict__ Af, uint4* __restrict__ Wf) {
    const int tid = blockIdx.x * 256 + threadIdx.x;
    if (tid < A_UNITS) {
        const int lane = tid & 63;
        const int ks   = (tid >> 6) & 1;
        const int kc   = (tid >> 7) & 15;
        const int mtg  = tid >> 11;
        const int row  = mtg * 16 + (lane & 15);
        const int k    = kc * 64 + ks * 32 + ((lane >> 4) << 3);
        const float* src = emb + (size_t)row * D_DIM + k;
        Af[tid] = pack8u(*(const float4*)src, *(const float4*)(src + 4));
    } else {
        const int j    = tid - A_UNITS;          // 0..16383
        const int kc   = j >> 10;
        const int r    = j & 1023;
        const int g    = r >> 6;                 // ks*8 + CT
        const int lane = r & 63;
        const int n    = (g & 7) * 16 + (lane & 15);
        const int k    = kc * 64 + (g >> 3) * 32 + ((lane >> 4) << 3);
        const float* src = W + (size_t)n * D_DIM + k;
        Wf[j] = pack8u(*(const float4*)src, *(const float4*)(src + 4));
    }
}

// 512 blocks x 256 threads (4 waves) = 2 blocks/CU. Block = 32 rows x 128
// cols x full K; wave w owns col-tiles {2w, 2w+1}. K-loop: zero LDS, zero
// barriers, ALL loads dense 16 B/lane from pre-swizzled Af/Wf. 4-stage
// register pipeline (kc&3 indexing, unroll 4 keeps loads across backedge).
__global__ __launch_bounds__(256, 2)
void qloss_kernel(const uint4* __restrict__ Af,
                  const uint4* __restrict__ Wf,
                  const float* __restrict__ bias,
                  const int*   __restrict__ didx,
                  const int*   __restrict__ dmsk,
                  float*       __restrict__ out)
{
    __shared__ __align__(16) unsigned char smem[16912];
    float* sL   = (float*)smem;                  // [32][132] f32 epilogue
    float* sRed = (float*)(smem + 16896);

    const int t    = threadIdx.x;
    const int w    = t >> 6;
    const int lane = t & 63;
    const int m15  = lane & 15;
    const int quad = lane >> 4;
    const int r0   = blockIdx.x * BM;
    const int mtg0 = blockIdx.x * 2;             // 16-row group indices

    // frag(mt, ks, kc): Af[(mtg*32 + kc*2 + ks)*64 + lane]
    const uint4* aP = Af + (size_t)mtg0 * 32 * 64 + lane;
    // frag(ks, j, kc):  Wf[kc*1024 + (ks*8 + 2w+j)*64 + lane]
    const uint4* bP = Wf + (size_t)(2 * w) * 64 + lane;

    f32x4 acc[2][2];
#pragma unroll
    for (int mt = 0; mt < 2; ++mt)
#pragma unroll
        for (int ct = 0; ct < 2; ++ct) acc[mt][ct] = (f32x4){0.f, 0.f, 0.f, 0.f};

    // 4-stage pipeline: stage s holds chunk kc with kc&3 == s
    Frag a[4][4], b[4][4];   // [stage][mt*2+ks] / [stage][ks*2+j]

#pragma unroll
    for (int s = 0; s < 4; ++s) {     // prologue: load chunks 0..3
#pragma unroll
        for (int mt = 0; mt < 2; ++mt)
#pragma unroll
            for (int ks = 0; ks < 2; ++ks)
                a[s][mt * 2 + ks].u = aP[(size_t)(mt * 32 * 64 * 16 / 16) + (s * 2 + ks) * 64];
#pragma unroll
        for (int ks = 0; ks < 2; ++ks)
#pragma unroll
            for (int j = 0; j < 2; ++j)
                b[s][ks * 2 + j].u = bP[(size_t)s * 1024 + (ks * 8 + j) * 64];
    }

#pragma unroll 4
    for (int kc = 0; kc < NCHUNK; ++kc) {
        const int s = kc & 3;
        // compute chunk kc from stage s
#pragma unroll
        for (int ks = 0; ks < 2; ++ks) {
            const half8 a0 = a[s][0 * 2 + ks].h;
            const half8 a1 = a[s][1 * 2 + ks].h;
            acc[0][0] = __builtin_amdgcn_mfma_f32_16x16x32_f16(a0, b[s][ks * 2 + 0].h, acc[0][0], 0, 0, 0);
            acc[0][1] = __builtin_amdgcn_mfma_f32_16x16x32_f16(a0, b[s][ks * 2 + 1].h, acc[0][1], 0, 0, 0);
            acc[1][0] = __builtin_amdgcn_mfma_f32_16x16x32_f16(a1, b[s][ks * 2 + 0].h, acc[1][0], 0, 0, 0);
            acc[1][1] = __builtin_amdgcn_mfma_f32_16x16x32_f16(a1, b[s][ks * 2 + 1].h, acc[1][1], 0, 0, 0);
        }
        // refill stage s with chunk kc+4 (3 stages of cover before use)
        if (kc + 4 < NCHUNK) {
            const int kn = kc + 4;
#pragma unroll
            for (int mt = 0; mt < 2; ++mt)
#pragma unroll
                for (int ks = 0; ks < 2; ++ks)
                    a[s][mt * 2 + ks].u = aP[(size_t)mt * 32 * 64 + (kn * 2 + ks) * 64];
#pragma unroll
            for (int ks = 0; ks < 2; ++ks)
#pragma unroll
                for (int j = 0; j < 2; ++j)
                    b[s][ks * 2 + j].u = bP[(size_t)kn * 1024 + (ks * 8 + j) * 64];
        }
    }

    // ---- epilogue (only barriers in the kernel) ----
    const int CT0 = w * 2;
    const float b0v = bias[CT0 * 16 + m15];
    const float b1v = bias[(CT0 + 1) * 16 + m15];
#pragma unroll
    for (int mt = 0; mt < 2; ++mt)
#pragma unroll
        for (int i = 0; i < 4; ++i) {
            const int row = mt * 16 + quad * 4 + i;
            sL[row * SL_STRIDE + CT0 * 16 + m15]       = acc[mt][0][i] + b0v;
            sL[row * SL_STRIDE + (CT0 + 1) * 16 + m15] = acc[mt][1][i] + b1v;
        }
    __syncthreads();

    // softmax: 8 threads/row, 16 cols each
    {
        const int row = t >> 3, s = t & 7;
        float* base = &sL[row * SL_STRIDE + s * 16];
        float v[16];
#pragma unroll
        for (int j = 0; j < 4; ++j) *(float4*)&v[j * 4] = *(const float4*)(base + j * 4);
        float m = -1e30f;
#pragma unroll
        for (int j = 0; j < 16; ++j) m = fmaxf(m, v[j]);
#pragma unroll
        for (int off = 1; off < 8; off <<= 1) m = fmaxf(m, __shfl_xor(m, off));
        float ssum = 0.f;
#pragma unroll
        for (int j = 0; j < 16; ++j) { v[j] = __expf(v[j] - m); ssum += v[j]; }
#pragma unroll
        for (int off = 1; off < 8; off <<= 1) ssum += __shfl_xor(ssum, off);
        const float inv = 1.0f / ssum;
#pragma unroll
        for (int j = 0; j < 16; ++j) v[j] *= inv;
#pragma unroll
        for (int j = 0; j < 4; ++j) *(float4*)(base + j * 4) = *(const float4*)&v[j * 4];
    }
    __syncthreads();

    // gather: 384 (row, j) entries; block partial -> one atomicAdd
    float p = 0.f;
#pragma unroll
    for (int i = t; i < BM * VLn; i += 256) {
        const int gi  = r0 * VLn + i;
        const int row = i / VLn;
        const int idx = didx[gi];
        const int mk  = dmsk[gi];
        p += mk ? sL[row * SL_STRIDE + idx] : 0.f;
    }
#pragma unroll
    for (int off = 1; off < 64; off <<= 1) p += __shfl_xor(p, off);
    if (lane == 0) sRed[w] = p;
    __syncthreads();
    if (t == 0)
        atomicAdd(out, (sRed[0] + sRed[1] + sRed[2] + sRed[3]) * (1.0f / 65536.0f));
}

extern "C" void kernel_launch(void* const* d_in, const int* in_sizes, int n_in,
                              void* d_out, int out_size, void* d_ws, size_t ws_size,
                              hipStream_t stream) {
    const float* emb  = (const float*)d_in[0];
    const float* W    = (const float*)d_in[1];
    const float* bias = (const float*)d_in[2];
    const int*   didx = (const int*)d_in[3];
    const int*   dmsk = (const int*)d_in[4];
    float* out = (float*)d_out;

    uint4* Af = (uint4*)d_ws;                          // 32 MB swizzled f16 A
    uint4* Wf = (uint4*)((char*)d_ws + 33554432);      // 256 KB swizzled f16 W

    hipMemsetAsync(out, 0, sizeof(float), stream);
    conv_ab<<<(A_UNITS + W_UNITS) / 256, 256, 0, stream>>>(emb, W, Af, Wf);
    qloss_kernel<<<GRID, 256, 0, stream>>>(Af, Wf, bias, didx, dmsk, out);
}